// Round 1
// baseline (356.786 us; speedup 1.0000x reference)
//
#include <hip/hip_runtime.h>
#include <hip/hip_bf16.h>
#include <stdint.h>

typedef __bf16 bf16;
typedef __bf16 bf16x8 __attribute__((ext_vector_type(8)));
typedef float f32x4 __attribute__((ext_vector_type(4)));

#define BATCH 4
#define SEQ   2048
#define DIM   1024
#define NH    16
#define HD    64

#define MFMA(a, b, c) __builtin_amdgcn_mfma_f32_16x16x32_bf16((a), (b), (c), 0, 0, 0)

// global -> LDS direct copy, 16B per lane. LDS dest must be wave-uniform.
#define GLOAD16(gsrc, ldst)                                                        \
  __builtin_amdgcn_global_load_lds(                                                \
      (__attribute__((address_space(1))) unsigned int*)(void*)(gsrc),              \
      (__attribute__((address_space(3))) unsigned int*)(ldst), 16, 0, 0)

// ---------------------------------------------------------------------------
// Weight conversion: f32 -> bf16, 4 tensors of DIM*DIM each.
// ---------------------------------------------------------------------------
__global__ __launch_bounds__(256) void cvt_w_kernel(
    const float* __restrict__ w0, const float* __restrict__ w1,
    const float* __restrict__ w2, const float* __restrict__ w3,
    bf16* __restrict__ o0, bf16* __restrict__ o1,
    bf16* __restrict__ o2, bf16* __restrict__ o3) {
  const float* s;
  bf16* d;
  switch (blockIdx.y) {
    case 0: s = w0; d = o0; break;
    case 1: s = w1; d = o1; break;
    case 2: s = w2; d = o2; break;
    default: s = w3; d = o3; break;
  }
  const int i = (blockIdx.x * 256 + threadIdx.x) * 4;
  const float4 v = *(const float4*)(s + i);
  ushort4 o;
  o.x = __builtin_bit_cast(unsigned short, (bf16)v.x);
  o.y = __builtin_bit_cast(unsigned short, (bf16)v.y);
  o.z = __builtin_bit_cast(unsigned short, (bf16)v.z);
  o.w = __builtin_bit_cast(unsigned short, (bf16)v.w);
  *(ushort4*)((unsigned short*)d + i) = o;
}

// ---------------------------------------------------------------------------
// Projection GEMM: C[m,n] = sum_k A[m,k] * W[n,k] + bias[n]   (nn.Linear)
// A: f32 [8192,1024] (query/key_in/value, reg-staged + converted to bf16)
// W: bf16 [1024,1024] row-major (= B^T layout), staged via global_load_lds
// z=0: out = bf16((C)*0.125) row-major  (Q, 1/sqrt(hd) folded in)
// z=1: out = bf16(C) row-major          (K)
// z=2: out = bf16(C) transposed to [B][DIM][SEQ]  (Vt, for contiguous PV)
// ---------------------------------------------------------------------------
struct ProjArgs {
  const float* A[3];
  const bf16*  W[3];
  const float* bias[3];
  bf16*        out[3];
};

__global__ __launch_bounds__(256, 2) void proj_gemm(ProjArgs p) {
  const int z = blockIdx.z;
  const float* __restrict__ A    = p.A[z];
  const bf16*  __restrict__ W    = p.W[z];
  const float* __restrict__ bias = p.bias[z];
  bf16*        __restrict__ out  = p.out[z];

  __shared__ bf16 Ab[128 * 32];  // [row 128][k 32], 64B rows, XOR-swizzled
  __shared__ bf16 Bb[128 * 32];

  const int tid  = threadIdx.x;
  const int wave = tid >> 6, lane = tid & 63;
  const int r = lane & 15, g = lane >> 4;
  const int m0 = blockIdx.y * 128, n0 = blockIdx.x * 128;
  const int wm = (wave >> 1) * 64, wn = (wave & 1) * 64;

  f32x4 acc[4][4] = {};

  // A staging: each lane owns row tid/2, 16 k-elements (64B f32 -> 32B bf16)
  const int arow = tid >> 1;
  const int ak   = (tid & 1) * 16;  // element offset within BK
  const float* aptr = A + (size_t)(m0 + arow) * DIM + ak;
  const int aswz = (arow & 3) << 4;
  char* alds = (char*)Ab + arow * 64;

  // B staging (global_load_lds): wave covers 32 rows, 4 lanes/64B row
  const int brow0 = wave * 32;
  const int bsub  = lane >> 2;
  const int bcb   = (lane & 3) * 16;

  for (int k0 = 0; k0 < DIM; k0 += 32) {
    // --- stage B (async) ---
#pragma unroll
    for (int i = 0; i < 2; ++i) {
      const int row = brow0 + i * 16 + bsub;
      const char* src =
          (const char*)(W + (size_t)(n0 + row) * DIM + k0) + (bcb ^ ((row & 3) << 4));
      GLOAD16(src, (char*)Bb + (brow0 + i * 16) * 64);
    }
    // --- stage A: f32 load, cvt, swizzled ds_write ---
    const float4 v0 = *(const float4*)(aptr + k0 + 0);
    const float4 v1 = *(const float4*)(aptr + k0 + 4);
    const float4 v2 = *(const float4*)(aptr + k0 + 8);
    const float4 v3 = *(const float4*)(aptr + k0 + 12);
    bf16x8 p0, p1;
    p0[0] = (bf16)v0.x; p0[1] = (bf16)v0.y; p0[2] = (bf16)v0.z; p0[3] = (bf16)v0.w;
    p0[4] = (bf16)v1.x; p0[5] = (bf16)v1.y; p0[6] = (bf16)v1.z; p0[7] = (bf16)v1.w;
    p1[0] = (bf16)v2.x; p1[1] = (bf16)v2.y; p1[2] = (bf16)v2.z; p1[3] = (bf16)v2.w;
    p1[4] = (bf16)v3.x; p1[5] = (bf16)v3.y; p1[6] = (bf16)v3.z; p1[7] = (bf16)v3.w;
    *(bf16x8*)(alds + ((ak * 2 + 0)  ^ aswz)) = p0;
    *(bf16x8*)(alds + ((ak * 2 + 16) ^ aswz)) = p1;

    __syncthreads();

    bf16x8 af[4], bfr[4];
#pragma unroll
    for (int mt = 0; mt < 4; ++mt) {
      const int mr = wm + mt * 16 + r;
      af[mt] = *(bf16x8*)((char*)Ab + mr * 64 + ((g * 16) ^ ((mr & 3) << 4)));
    }
#pragma unroll
    for (int nt = 0; nt < 4; ++nt) {
      const int nr = wn + nt * 16 + r;
      bfr[nt] = *(bf16x8*)((char*)Bb + nr * 64 + ((g * 16) ^ ((nr & 3) << 4)));
    }
#pragma unroll
    for (int mt = 0; mt < 4; ++mt)
#pragma unroll
      for (int nt = 0; nt < 4; ++nt)
        acc[mt][nt] = MFMA(af[mt], bfr[nt], acc[mt][nt]);

    __syncthreads();
  }

  // --- epilogue ---  C/D layout: row = g*4 + reg, col = r (per 16x16 tile)
  if (z == 2) {
    // write V transposed: Vt[b][n][t], layout [BATCH][DIM][SEQ]
#pragma unroll
    for (int nt = 0; nt < 4; ++nt) {
      const int n = n0 + wn + nt * 16 + r;
      const float bn = bias[n];
#pragma unroll
      for (int mt = 0; mt < 4; ++mt) {
        const int m = m0 + wm + mt * 16 + g * 4;  // 4 consecutive t per lane
        const int b = m >> 11, t = m & 2047;
        ushort4 pk;
        pk.x = __builtin_bit_cast(unsigned short, (bf16)(acc[mt][nt][0] + bn));
        pk.y = __builtin_bit_cast(unsigned short, (bf16)(acc[mt][nt][1] + bn));
        pk.z = __builtin_bit_cast(unsigned short, (bf16)(acc[mt][nt][2] + bn));
        pk.w = __builtin_bit_cast(unsigned short, (bf16)(acc[mt][nt][3] + bn));
        *(ushort4*)((unsigned short*)out + (((size_t)(b * DIM + n)) << 11) + t) = pk;
      }
    }
  } else {
    const float scale = (z == 0) ? 0.125f : 1.0f;  // fold 1/sqrt(64) into Q
#pragma unroll
    for (int mt = 0; mt < 4; ++mt)
#pragma unroll
      for (int nt = 0; nt < 4; ++nt) {
        const int n = n0 + wn + nt * 16 + r;
        const float bn = bias[n];
#pragma unroll
        for (int i = 0; i < 4; ++i) {
          const int m = m0 + wm + mt * 16 + g * 4 + i;
          out[(size_t)m * DIM + n] = (bf16)((acc[mt][nt][i] + bn) * scale);
        }
      }
  }
}

// ---------------------------------------------------------------------------
// Fused attention: per (b,h), Q-block 64 rows (4 waves x 16), KV tiles of 64.
// Q pre-scaled by 1/8. K: [B,SEQ,DIM] bf16; Vt: [B,DIM,SEQ] bf16.
// Online softmax in fp32; P through padded per-wave LDS.
// ---------------------------------------------------------------------------
__global__ __launch_bounds__(256, 2) void attn_kernel(
    const bf16* __restrict__ Q, const bf16* __restrict__ K,
    const bf16* __restrict__ Vt, bf16* __restrict__ ctx) {
  __shared__ bf16 Kb[64 * 64];      // [kv 64][d 64], 128B rows, XOR-swizzled
  __shared__ bf16 Vb[64 * 64];      // [d 64][kv 64], 128B rows, XOR-swizzled
  __shared__ bf16 Pb[4][16][72];    // per-wave P, rows padded to 144B

  const int tid  = threadIdx.x;
  const int wave = tid >> 6, lane = tid & 63;
  const int r = lane & 15, g = lane >> 4;
  const int bh = blockIdx.y;
  const int b = bh >> 4, h = bh & 15;
  const int t0 = blockIdx.x * 64;

  // Q fragments (A operand: row = lane%16, k = (lane/16)*8 + j), hoisted
  const bf16* qrow = Q + ((size_t)(b * SEQ + t0 + wave * 16 + r) * DIM + h * HD);
  bf16x8 qf[2];
  qf[0] = *(const bf16x8*)(qrow + g * 8);
  qf[1] = *(const bf16x8*)(qrow + 32 + g * 8);

  f32x4 accO[4] = {};
  float m_i[4], l_i[4];
#pragma unroll
  for (int i = 0; i < 4; ++i) { m_i[i] = -1e30f; l_i[i] = 0.0f; }

  const bf16* Kbase = K + (size_t)(b * SEQ) * DIM + h * HD;
  const bf16* Vbase = Vt + (size_t)(b * DIM + h * HD) * SEQ;

  const int srr = lane >> 3;         // staging sub-row (8 lanes per 128B row)
  const int scb = (lane & 7) * 16;   // staging byte col

  for (int kv0 = 0; kv0 < SEQ; kv0 += 64) {
    // --- stage K tile and Vt tile (each wave: 16 rows of each) ---
#pragma unroll
    for (int i = 0; i < 2; ++i) {
      const int row = wave * 16 + i * 8 + srr;
      const char* ksrc =
          (const char*)(Kbase + (size_t)(kv0 + row) * DIM) + (scb ^ ((row & 7) << 4));
      GLOAD16(ksrc, (char*)Kb + (wave * 16 + i * 8) * 128);
      const char* vsrc =
          (const char*)(Vbase + (size_t)row * SEQ + kv0) + (scb ^ ((row & 7) << 4));
      GLOAD16(vsrc, (char*)Vb + (wave * 16 + i * 8) * 128);
    }
    __syncthreads();

    // --- S = Q K^T (pre-scaled) ---
    f32x4 s[4];
#pragma unroll
    for (int nt = 0; nt < 4; ++nt) {
      s[nt] = f32x4{0.f, 0.f, 0.f, 0.f};
      const int kvr = nt * 16 + r;
#pragma unroll
      for (int ks = 0; ks < 2; ++ks) {
        bf16x8 kf =
            *(bf16x8*)((char*)Kb + kvr * 128 + ((ks * 64 + g * 16) ^ ((kvr & 7) << 4)));
        s[nt] = MFMA(qf[ks], kf, s[nt]);
      }
    }

    // --- online softmax (rows = g*4+i, cols spread over 16 lanes of group) ---
    float alpha[4];
#pragma unroll
    for (int i = 0; i < 4; ++i) {
      float t = fmaxf(fmaxf(s[0][i], s[1][i]), fmaxf(s[2][i], s[3][i]));
      t = fmaxf(t, __shfl_xor(t, 1));
      t = fmaxf(t, __shfl_xor(t, 2));
      t = fmaxf(t, __shfl_xor(t, 4));
      t = fmaxf(t, __shfl_xor(t, 8));
      const float mn = fmaxf(m_i[i], t);
      alpha[i] = __expf(m_i[i] - mn);
      m_i[i] = mn;
      l_i[i] *= alpha[i];
    }
    float rs[4] = {0.f, 0.f, 0.f, 0.f};
#pragma unroll
    for (int nt = 0; nt < 4; ++nt)
#pragma unroll
      for (int i = 0; i < 4; ++i) {
        const float pv = __expf(s[nt][i] - m_i[i]);
        s[nt][i] = pv;
        rs[i] += pv;
      }
#pragma unroll
    for (int i = 0; i < 4; ++i) {
      float t = rs[i];
      t += __shfl_xor(t, 1);
      t += __shfl_xor(t, 2);
      t += __shfl_xor(t, 4);
      t += __shfl_xor(t, 8);
      l_i[i] += t;
    }
#pragma unroll
    for (int dt = 0; dt < 4; ++dt)
#pragma unroll
      for (int i = 0; i < 4; ++i) accO[dt][i] *= alpha[i];

    // --- P -> LDS (bf16) ---
#pragma unroll
    for (int nt = 0; nt < 4; ++nt)
#pragma unroll
      for (int i = 0; i < 4; ++i) Pb[wave][g * 4 + i][nt * 16 + r] = (bf16)s[nt][i];
    __syncthreads();

    // --- O += P V ---
#pragma unroll
    for (int ks = 0; ks < 2; ++ks) {
      const bf16x8 pf = *(bf16x8*)((char*)&Pb[wave][0][0] + r * 144 + ks * 64 + g * 16);
#pragma unroll
      for (int dt = 0; dt < 4; ++dt) {
        const int dr = dt * 16 + r;
        bf16x8 vf =
            *(bf16x8*)((char*)Vb + dr * 128 + ((ks * 64 + g * 16) ^ ((dr & 7) << 4)));
        accO[dt] = MFMA(pf, vf, accO[dt]);
      }
    }
    __syncthreads();
  }

  // --- normalize and write ctx (merged heads, bf16) ---
#pragma unroll
  for (int i = 0; i < 4; ++i) {
    const float inv = 1.0f / l_i[i];
    const size_t rowoff = (size_t)(b * SEQ + t0 + wave * 16 + g * 4 + i) * DIM + h * HD;
#pragma unroll
    for (int dt = 0; dt < 4; ++dt)
      ctx[rowoff + dt * 16 + r] = (bf16)(accO[dt][i] * inv);
  }
}

// ---------------------------------------------------------------------------
// Output GEMM: out[m,n] = sum_k ctx[m,k] * Wo[n,k] + bo[n], f32 output.
// Both operands bf16 via global_load_lds.
// ---------------------------------------------------------------------------
__global__ __launch_bounds__(256, 2) void out_gemm(
    const bf16* __restrict__ A, const bf16* __restrict__ W,
    const float* __restrict__ bias, float* __restrict__ out) {
  __shared__ bf16 Ab[128 * 32];
  __shared__ bf16 Bb[128 * 32];

  const int tid  = threadIdx.x;
  const int wave = tid >> 6, lane = tid & 63;
  const int r = lane & 15, g = lane >> 4;
  const int m0 = blockIdx.y * 128, n0 = blockIdx.x * 128;
  const int wm = (wave >> 1) * 64, wn = (wave & 1) * 64;

  f32x4 acc[4][4] = {};

  const int srow0 = wave * 32;
  const int ssub  = lane >> 2;
  const int scb   = (lane & 3) * 16;

  for (int k0 = 0; k0 < DIM; k0 += 32) {
#pragma unroll
    for (int i = 0; i < 2; ++i) {
      const int row = srow0 + i * 16 + ssub;
      const int sw = (row & 3) << 4;
      const char* asrc = (const char*)(A + (size_t)(m0 + row) * DIM + k0) + (scb ^ sw);
      GLOAD16(asrc, (char*)Ab + (srow0 + i * 16) * 64);
      const char* bsrc = (const char*)(W + (size_t)(n0 + row) * DIM + k0) + (scb ^ sw);
      GLOAD16(bsrc, (char*)Bb + (srow0 + i * 16) * 64);
    }
    __syncthreads();

    bf16x8 af[4], bfr[4];
#pragma unroll
    for (int mt = 0; mt < 4; ++mt) {
      const int mr = wm + mt * 16 + r;
      af[mt] = *(bf16x8*)((char*)Ab + mr * 64 + ((g * 16) ^ ((mr & 3) << 4)));
    }
#pragma unroll
    for (int nt = 0; nt < 4; ++nt) {
      const int nr = wn + nt * 16 + r;
      bfr[nt] = *(bf16x8*)((char*)Bb + nr * 64 + ((g * 16) ^ ((nr & 3) << 4)));
    }
#pragma unroll
    for (int mt = 0; mt < 4; ++mt)
#pragma unroll
      for (int nt = 0; nt < 4; ++nt)
        acc[mt][nt] = MFMA(af[mt], bfr[nt], acc[mt][nt]);

    __syncthreads();
  }

#pragma unroll
  for (int mt = 0; mt < 4; ++mt)
#pragma unroll
    for (int nt = 0; nt < 4; ++nt) {
      const int n = n0 + wn + nt * 16 + r;
      const float bn = bias[n];
#pragma unroll
      for (int i = 0; i < 4; ++i) {
        const int m = m0 + wm + mt * 16 + g * 4 + i;
        out[(size_t)m * DIM + n] = acc[mt][nt][i] + bn;
      }
    }
}

// ---------------------------------------------------------------------------
// kernel_launch
// ---------------------------------------------------------------------------
extern "C" void kernel_launch(void* const* d_in, const int* in_sizes, int n_in,
                              void* d_out, int out_size, void* d_ws, size_t ws_size,
                              hipStream_t stream) {
  const float* query  = (const float*)d_in[0];
  const float* key_in = (const float*)d_in[1];
  const float* value  = (const float*)d_in[2];
  const float* Wq = (const float*)d_in[3];
  const float* bq = (const float*)d_in[4];
  const float* Wk = (const float*)d_in[5];
  const float* bk = (const float*)d_in[6];
  const float* Wv = (const float*)d_in[7];
  const float* bv = (const float*)d_in[8];
  const float* Wo = (const float*)d_in[9];
  const float* bo = (const float*)d_in[10];

  // workspace layout (72 MiB total):
  //   4 x 2MiB  bf16 weights
  //   4 x 16MiB bf16 tensors: Q, K, Vt (transposed V), ctx
  char* ws = (char*)d_ws;
  const size_t WSZ = (size_t)DIM * DIM * sizeof(bf16);
  const size_t TSZ = (size_t)BATCH * SEQ * DIM * sizeof(bf16);
  bf16* Wq_b = (bf16*)(ws);
  bf16* Wk_b = (bf16*)(ws + WSZ);
  bf16* Wv_b = (bf16*)(ws + 2 * WSZ);
  bf16* Wo_b = (bf16*)(ws + 3 * WSZ);
  bf16* Q_b  = (bf16*)(ws + 4 * WSZ);
  bf16* K_b  = (bf16*)(ws + 4 * WSZ + TSZ);
  bf16* Vt_b = (bf16*)(ws + 4 * WSZ + 2 * TSZ);
  bf16* C_b  = (bf16*)(ws + 4 * WSZ + 3 * TSZ);

  cvt_w_kernel<<<dim3(DIM * DIM / (256 * 4), 4), 256, 0, stream>>>(
      Wq, Wk, Wv, Wo, Wq_b, Wk_b, Wv_b, Wo_b);

  ProjArgs pa;
  pa.A[0] = query; pa.A[1] = key_in; pa.A[2] = value;
  pa.W[0] = Wq_b;  pa.W[1] = Wk_b;   pa.W[2] = Wv_b;
  pa.bias[0] = bq; pa.bias[1] = bk;  pa.bias[2] = bv;
  pa.out[0] = Q_b; pa.out[1] = K_b;  pa.out[2] = Vt_b;
  proj_gemm<<<dim3(DIM / 128, BATCH * SEQ / 128, 3), 256, 0, stream>>>(pa);

  attn_kernel<<<dim3(SEQ / 64, BATCH * NH), 256, 0, stream>>>(Q_b, K_b, Vt_b, C_b);

  out_gemm<<<dim3(DIM / 128, BATCH * SEQ / 128), 256, 0, stream>>>(
      C_b, Wo_b, bo, (float*)d_out);
}

// Round 2
// 266.155 us; speedup vs baseline: 1.3405x; 1.3405x over previous
//
#include <hip/hip_runtime.h>
#include <hip/hip_bf16.h>
#include <stdint.h>

typedef __bf16 bf16;
typedef __bf16 bf16x8 __attribute__((ext_vector_type(8)));
typedef float f32x4 __attribute__((ext_vector_type(4)));

#define BATCH 4
#define SEQ   2048
#define DIM   1024
#define NH    16
#define HD    64

// Q projection is pre-scaled by (1/sqrt(HD)) * log2(e) so attention softmax
// runs entirely in the exp2 domain (saves one VALU mul per exp).
#define QSCALE 0.18033688011112042f  // 0.125 * 1.4426950408889634

#define MFMA(a, b, c) __builtin_amdgcn_mfma_f32_16x16x32_bf16((a), (b), (c), 0, 0, 0)

// global -> LDS direct copy, 16B per lane. LDS dest must be wave-uniform.
#define GLOAD16(gsrc, ldst)                                                        \
  __builtin_amdgcn_global_load_lds(                                                \
      (__attribute__((address_space(1))) unsigned int*)(void*)(gsrc),              \
      (__attribute__((address_space(3))) unsigned int*)(ldst), 16, 0, 0)

static __device__ __forceinline__ float fast_exp2(float x) {
#if __has_builtin(__builtin_amdgcn_exp2f)
  return __builtin_amdgcn_exp2f(x);
#else
  return exp2f(x);
#endif
}

// ---------------------------------------------------------------------------
// Weight conversion: f32 -> bf16, 4 tensors of DIM*DIM each.
// ---------------------------------------------------------------------------
__global__ __launch_bounds__(256) void cvt_w_kernel(
    const float* __restrict__ w0, const float* __restrict__ w1,
    const float* __restrict__ w2, const float* __restrict__ w3,
    bf16* __restrict__ o0, bf16* __restrict__ o1,
    bf16* __restrict__ o2, bf16* __restrict__ o3) {
  const float* s;
  bf16* d;
  switch (blockIdx.y) {
    case 0: s = w0; d = o0; break;
    case 1: s = w1; d = o1; break;
    case 2: s = w2; d = o2; break;
    default: s = w3; d = o3; break;
  }
  const int i = (blockIdx.x * 256 + threadIdx.x) * 4;
  const float4 v = *(const float4*)(s + i);
  ushort4 o;
  o.x = __builtin_bit_cast(unsigned short, (bf16)v.x);
  o.y = __builtin_bit_cast(unsigned short, (bf16)v.y);
  o.z = __builtin_bit_cast(unsigned short, (bf16)v.z);
  o.w = __builtin_bit_cast(unsigned short, (bf16)v.w);
  *(ushort4*)((unsigned short*)d + i) = o;
}

// ---------------------------------------------------------------------------
// Projection GEMM: C[m,n] = sum_k A[m,k] * W[n,k] + bias[n]   (nn.Linear)
// z=0: out = bf16(C * QSCALE) row-major  (Q, softmax scale folded in)
// z=1: out = bf16(C) row-major           (K)
// z=2: out = bf16(C) transposed to [B][DIM][SEQ]  (Vt, for contiguous PV)
// ---------------------------------------------------------------------------
struct ProjArgs {
  const float* A[3];
  const bf16*  W[3];
  const float* bias[3];
  bf16*        out[3];
};

__global__ __launch_bounds__(256, 2) void proj_gemm(ProjArgs p) {
  const int z = blockIdx.z;
  const float* __restrict__ A    = p.A[z];
  const bf16*  __restrict__ W    = p.W[z];
  const float* __restrict__ bias = p.bias[z];
  bf16*        __restrict__ out  = p.out[z];

  __shared__ bf16 Ab[128 * 32];  // [row 128][k 32], 64B rows, XOR-swizzled
  __shared__ bf16 Bb[128 * 32];

  const int tid  = threadIdx.x;
  const int wave = tid >> 6, lane = tid & 63;
  const int r = lane & 15, g = lane >> 4;
  const int m0 = blockIdx.y * 128, n0 = blockIdx.x * 128;
  const int wm = (wave >> 1) * 64, wn = (wave & 1) * 64;

  f32x4 acc[4][4] = {};

  const int arow = tid >> 1;
  const int ak   = (tid & 1) * 16;
  const float* aptr = A + (size_t)(m0 + arow) * DIM + ak;
  const int aswz = (arow & 3) << 4;
  char* alds = (char*)Ab + arow * 64;

  const int brow0 = wave * 32;
  const int bsub  = lane >> 2;
  const int bcb   = (lane & 3) * 16;

  for (int k0 = 0; k0 < DIM; k0 += 32) {
#pragma unroll
    for (int i = 0; i < 2; ++i) {
      const int row = brow0 + i * 16 + bsub;
      const char* src =
          (const char*)(W + (size_t)(n0 + row) * DIM + k0) + (bcb ^ ((row & 3) << 4));
      GLOAD16(src, (char*)Bb + (brow0 + i * 16) * 64);
    }
    const float4 v0 = *(const float4*)(aptr + k0 + 0);
    const float4 v1 = *(const float4*)(aptr + k0 + 4);
    const float4 v2 = *(const float4*)(aptr + k0 + 8);
    const float4 v3 = *(const float4*)(aptr + k0 + 12);
    bf16x8 p0, p1;
    p0[0] = (bf16)v0.x; p0[1] = (bf16)v0.y; p0[2] = (bf16)v0.z; p0[3] = (bf16)v0.w;
    p0[4] = (bf16)v1.x; p0[5] = (bf16)v1.y; p0[6] = (bf16)v1.z; p0[7] = (bf16)v1.w;
    p1[0] = (bf16)v2.x; p1[1] = (bf16)v2.y; p1[2] = (bf16)v2.z; p1[3] = (bf16)v2.w;
    p1[4] = (bf16)v3.x; p1[5] = (bf16)v3.y; p1[6] = (bf16)v3.z; p1[7] = (bf16)v3.w;
    *(bf16x8*)(alds + ((ak * 2 + 0)  ^ aswz)) = p0;
    *(bf16x8*)(alds + ((ak * 2 + 16) ^ aswz)) = p1;

    __syncthreads();

    bf16x8 af[4], bfr[4];
#pragma unroll
    for (int mt = 0; mt < 4; ++mt) {
      const int mr = wm + mt * 16 + r;
      af[mt] = *(bf16x8*)((char*)Ab + mr * 64 + ((g * 16) ^ ((mr & 3) << 4)));
    }
#pragma unroll
    for (int nt = 0; nt < 4; ++nt) {
      const int nr = wn + nt * 16 + r;
      bfr[nt] = *(bf16x8*)((char*)Bb + nr * 64 + ((g * 16) ^ ((nr & 3) << 4)));
    }
#pragma unroll
    for (int mt = 0; mt < 4; ++mt)
#pragma unroll
      for (int nt = 0; nt < 4; ++nt)
        acc[mt][nt] = MFMA(af[mt], bfr[nt], acc[mt][nt]);

    __syncthreads();
  }

  if (z == 2) {
#pragma unroll
    for (int nt = 0; nt < 4; ++nt) {
      const int n = n0 + wn + nt * 16 + r;
      const float bn = bias[n];
#pragma unroll
      for (int mt = 0; mt < 4; ++mt) {
        const int m = m0 + wm + mt * 16 + g * 4;
        const int b = m >> 11, t = m & 2047;
        ushort4 pk;
        pk.x = __builtin_bit_cast(unsigned short, (bf16)(acc[mt][nt][0] + bn));
        pk.y = __builtin_bit_cast(unsigned short, (bf16)(acc[mt][nt][1] + bn));
        pk.z = __builtin_bit_cast(unsigned short, (bf16)(acc[mt][nt][2] + bn));
        pk.w = __builtin_bit_cast(unsigned short, (bf16)(acc[mt][nt][3] + bn));
        *(ushort4*)((unsigned short*)out + (((size_t)(b * DIM + n)) << 11) + t) = pk;
      }
    }
  } else {
    const float scale = (z == 0) ? QSCALE : 1.0f;
#pragma unroll
    for (int mt = 0; mt < 4; ++mt)
#pragma unroll
      for (int nt = 0; nt < 4; ++nt) {
        const int n = n0 + wn + nt * 16 + r;
        const float bn = bias[n];
#pragma unroll
        for (int i = 0; i < 4; ++i) {
          const int m = m0 + wm + mt * 16 + g * 4 + i;
          out[(size_t)m * DIM + n] = (bf16)((acc[mt][nt][i] + bn) * scale);
        }
      }
  }
}

// ---------------------------------------------------------------------------
// Fused attention, swapped-QK^T structure.
// Block: 4 waves x 32 q-rows = 128 q-rows per (b,h). KV tiles of 64,
// double-buffered in LDS, one barrier per tile.
// S^T = mfma(K, Q): lane holds S[kv = nt*16 + g*4 + i][q = qt*16 + r]
//   -> per-q softmax is 16 lane-local values + 2 shfl_xor per reduce.
// Softmax in exp2/log2 domain (scale folded into Q), defer-max (THR=8).
// P routed via per-wave swizzled LDS to MFMA A-layout; PV from Vt tiles.
// ---------------------------------------------------------------------------
__global__ __launch_bounds__(256, 3) void attn_kernel(
    const bf16* __restrict__ Q, const bf16* __restrict__ K,
    const bf16* __restrict__ Vt, bf16* __restrict__ ctx) {
  __shared__ bf16 Kb[2][64 * 64];   // [kv 64][d 64], 128B rows, XOR-swizzled
  __shared__ bf16 Vb[2][64 * 64];   // [d 64][kv 64], 128B rows, XOR-swizzled
  __shared__ bf16 Pb[4][32 * 64];   // per-wave P[q 32][kv 64], XOR-swizzled

  const int tid  = threadIdx.x;
  const int wave = tid >> 6, lane = tid & 63;
  const int r = lane & 15, g = lane >> 4;
  const int bh = blockIdx.y;
  const int b = bh >> 4, h = bh & 15;
  const int q0 = blockIdx.x * 128 + wave * 32;

  // Q fragments (B operand): lane holds col q = qt*16 + r, k(d) = ks*32 + g*8 + j
  bf16x8 qf[2][2];
  {
    const bf16* qp = Q + ((size_t)(b * SEQ + q0 + r) * DIM + h * HD);
#pragma unroll
    for (int qt = 0; qt < 2; ++qt)
#pragma unroll
      for (int ks = 0; ks < 2; ++ks)
        qf[qt][ks] = *(const bf16x8*)(qp + (size_t)qt * 16 * DIM + ks * 32 + g * 8);
  }

  f32x4 accO[2][4] = {};            // [qt][dt]: q = qt*16+g*4+i, d = dt*16+r
  float m_i[2] = {-3e38f, -3e38f};  // running max (log2 domain), q = qt*16+r
  float l_i[2] = {0.f, 0.f};

  const bf16* Kbase = K + (size_t)(b * SEQ) * DIM + h * HD;
  const bf16* Vbase = Vt + (size_t)(b * DIM + h * HD) * SEQ;

  const int srr = lane >> 3;        // staged sub-row within 8-row group
  const int scb = (lane & 7) * 16;  // staged byte col
  const int swz = srr << 4;         // == (row&7)<<4 for staged rows

#define STAGE(buf, kv0)                                                             \
  do {                                                                              \
    _Pragma("unroll") for (int i_ = 0; i_ < 2; ++i_) {                              \
      const int row_ = wave * 16 + i_ * 8 + srr;                                    \
      const char* ks_ =                                                             \
          (const char*)(Kbase + (size_t)((kv0) + row_) * DIM) + (scb ^ swz);        \
      GLOAD16(ks_, (char*)&Kb[buf][0] + (wave * 16 + i_ * 8) * 128);                \
      const char* vs_ =                                                             \
          (const char*)(Vbase + (size_t)row_ * SEQ + (kv0)) + (scb ^ swz);          \
      GLOAD16(vs_, (char*)&Vb[buf][0] + (wave * 16 + i_ * 8) * 128);                \
    }                                                                               \
  } while (0)

  STAGE(0, 0);
  __syncthreads();

  const int NIT = SEQ / 64;
  for (int it = 0; it < NIT; ++it) {
    const int cur = it & 1;
    if (it + 1 < NIT) STAGE(cur ^ 1, (it + 1) * 64);

    // --- S^T = K·Q ---
    f32x4 s[2][4];
#pragma unroll
    for (int qt = 0; qt < 2; ++qt)
#pragma unroll
      for (int nt = 0; nt < 4; ++nt) s[qt][nt] = f32x4{0.f, 0.f, 0.f, 0.f};
#pragma unroll
    for (int nt = 0; nt < 4; ++nt) {
      const int kr = nt * 16 + r;
#pragma unroll
      for (int ks = 0; ks < 2; ++ks) {
        const bf16x8 kf = *(bf16x8*)((char*)&Kb[cur][0] + kr * 128 +
                                     ((ks * 64 + g * 16) ^ ((kr & 7) << 4)));
        s[0][nt] = MFMA(kf, qf[0][ks], s[0][nt]);
        s[1][nt] = MFMA(kf, qf[1][ks], s[1][nt]);
      }
    }

    // --- tile max (lane-local 16 + 2 shfl) ---
    float pm[2];
#pragma unroll
    for (int qt = 0; qt < 2; ++qt) {
      f32x4 m4;
#pragma unroll
      for (int i = 0; i < 4; ++i)
        m4[i] = fmaxf(fmaxf(s[qt][0][i], s[qt][1][i]), fmaxf(s[qt][2][i], s[qt][3][i]));
      float t = fmaxf(fmaxf(m4[0], m4[1]), fmaxf(m4[2], m4[3]));
      t = fmaxf(t, __shfl_xor(t, 16));
      t = fmaxf(t, __shfl_xor(t, 32));
      pm[qt] = t;
    }

    // --- defer-max: rescale only when the running max grew by > 8 (log2) ---
    const bool need = (pm[0] > m_i[0] + 8.0f) || (pm[1] > m_i[1] + 8.0f);
    if (__any(need)) {
      float alpha[2];
#pragma unroll
      for (int qt = 0; qt < 2; ++qt) {
        const float mn = fmaxf(m_i[qt], pm[qt]);
        alpha[qt] = fast_exp2(m_i[qt] - mn);
        m_i[qt] = mn;
        l_i[qt] *= alpha[qt];
      }
#pragma unroll
      for (int qt = 0; qt < 2; ++qt)
#pragma unroll
        for (int i = 0; i < 4; ++i) {
          const float a = __shfl(alpha[qt], g * 4 + i);
#pragma unroll
          for (int dt = 0; dt < 4; ++dt) accO[qt][dt][i] *= a;
        }
    }

    // --- P = exp2(S - m), row-sum, pack to bf16, stash in per-wave LDS ---
    float rs[2] = {0.f, 0.f};
#pragma unroll
    for (int qt = 0; qt < 2; ++qt) {
      const int row = qt * 16 + r;
      const int rsw = (row & 7) << 4;
#pragma unroll
      for (int nt = 0; nt < 4; ++nt) {
        f32x4 pv;
#pragma unroll
        for (int i = 0; i < 4; ++i) {
          pv[i] = fast_exp2(s[qt][nt][i] - m_i[qt]);
          rs[qt] += pv[i];
        }
        ushort4 pk;
        pk.x = __builtin_bit_cast(unsigned short, (bf16)pv[0]);
        pk.y = __builtin_bit_cast(unsigned short, (bf16)pv[1]);
        pk.z = __builtin_bit_cast(unsigned short, (bf16)pv[2]);
        pk.w = __builtin_bit_cast(unsigned short, (bf16)pv[3]);
        *(ushort4*)((char*)&Pb[wave][0] + row * 128 + ((nt * 32 + g * 8) ^ rsw)) = pk;
      }
      rs[qt] += __shfl_xor(rs[qt], 16);
      rs[qt] += __shfl_xor(rs[qt], 32);
      l_i[qt] += rs[qt];
    }

    // --- O += P·V ---
#pragma unroll
    for (int ss = 0; ss < 2; ++ss) {
      bf16x8 pf[2];
#pragma unroll
      for (int qt = 0; qt < 2; ++qt) {
        const int row = qt * 16 + r;
        pf[qt] = *(bf16x8*)((char*)&Pb[wave][0] + row * 128 +
                            ((ss * 64 + g * 16) ^ ((row & 7) << 4)));
      }
#pragma unroll
      for (int dt = 0; dt < 4; ++dt) {
        const int dr = dt * 16 + r;
        const bf16x8 vf = *(bf16x8*)((char*)&Vb[cur][0] + dr * 128 +
                                     ((ss * 64 + g * 16) ^ ((dr & 7) << 4)));
        accO[0][dt] = MFMA(pf[0], vf, accO[0][dt]);
        accO[1][dt] = MFMA(pf[1], vf, accO[1][dt]);
      }
    }

    __syncthreads();  // drains vmcnt(0): next tile's staging complete
  }
#undef STAGE

  // --- normalize (broadcast l to accO layout) and write ctx ---
#pragma unroll
  for (int qt = 0; qt < 2; ++qt)
#pragma unroll
    for (int i = 0; i < 4; ++i) {
      const float li = __shfl(l_i[qt], g * 4 + i);
      const float inv = 1.0f / li;
      const int qrow = q0 + qt * 16 + g * 4 + i;
      bf16* cp = ctx + (size_t)(b * SEQ + qrow) * DIM + h * HD;
#pragma unroll
      for (int dt = 0; dt < 4; ++dt)
        cp[dt * 16 + r] = (bf16)(accO[qt][dt][i] * inv);
    }
}

// ---------------------------------------------------------------------------
// Output GEMM: out[m,n] = sum_k ctx[m,k] * Wo[n,k] + bo[n], f32 output.
// ---------------------------------------------------------------------------
__global__ __launch_bounds__(256, 2) void out_gemm(
    const bf16* __restrict__ A, const bf16* __restrict__ W,
    const float* __restrict__ bias, float* __restrict__ out) {
  __shared__ bf16 Ab[128 * 32];
  __shared__ bf16 Bb[128 * 32];

  const int tid  = threadIdx.x;
  const int wave = tid >> 6, lane = tid & 63;
  const int r = lane & 15, g = lane >> 4;
  const int m0 = blockIdx.y * 128, n0 = blockIdx.x * 128;
  const int wm = (wave >> 1) * 64, wn = (wave & 1) * 64;

  f32x4 acc[4][4] = {};

  const int srow0 = wave * 32;
  const int ssub  = lane >> 2;
  const int scb   = (lane & 3) * 16;

  for (int k0 = 0; k0 < DIM; k0 += 32) {
#pragma unroll
    for (int i = 0; i < 2; ++i) {
      const int row = srow0 + i * 16 + ssub;
      const int sw = (row & 3) << 4;
      const char* asrc = (const char*)(A + (size_t)(m0 + row) * DIM + k0) + (scb ^ sw);
      GLOAD16(asrc, (char*)Ab + (srow0 + i * 16) * 64);
      const char* bsrc = (const char*)(W + (size_t)(n0 + row) * DIM + k0) + (scb ^ sw);
      GLOAD16(bsrc, (char*)Bb + (srow0 + i * 16) * 64);
    }
    __syncthreads();

    bf16x8 af[4], bfr[4];
#pragma unroll
    for (int mt = 0; mt < 4; ++mt) {
      const int mr = wm + mt * 16 + r;
      af[mt] = *(bf16x8*)((char*)Ab + mr * 64 + ((g * 16) ^ ((mr & 3) << 4)));
    }
#pragma unroll
    for (int nt = 0; nt < 4; ++nt) {
      const int nr = wn + nt * 16 + r;
      bfr[nt] = *(bf16x8*)((char*)Bb + nr * 64 + ((g * 16) ^ ((nr & 3) << 4)));
    }
#pragma unroll
    for (int mt = 0; mt < 4; ++mt)
#pragma unroll
      for (int nt = 0; nt < 4; ++nt)
        acc[mt][nt] = MFMA(af[mt], bfr[nt], acc[mt][nt]);

    __syncthreads();
  }

#pragma unroll
  for (int mt = 0; mt < 4; ++mt)
#pragma unroll
    for (int nt = 0; nt < 4; ++nt) {
      const int n = n0 + wn + nt * 16 + r;
      const float bn = bias[n];
#pragma unroll
      for (int i = 0; i < 4; ++i) {
        const int m = m0 + wm + mt * 16 + g * 4 + i;
        out[(size_t)m * DIM + n] = acc[mt][nt][i] + bn;
      }
    }
}

// ---------------------------------------------------------------------------
// kernel_launch
// ---------------------------------------------------------------------------
extern "C" void kernel_launch(void* const* d_in, const int* in_sizes, int n_in,
                              void* d_out, int out_size, void* d_ws, size_t ws_size,
                              hipStream_t stream) {
  const float* query  = (const float*)d_in[0];
  const float* key_in = (const float*)d_in[1];
  const float* value  = (const float*)d_in[2];
  const float* Wq = (const float*)d_in[3];
  const float* bq = (const float*)d_in[4];
  const float* Wk = (const float*)d_in[5];
  const float* bk = (const float*)d_in[6];
  const float* Wv = (const float*)d_in[7];
  const float* bv = (const float*)d_in[8];
  const float* Wo = (const float*)d_in[9];
  const float* bo = (const float*)d_in[10];

  char* ws = (char*)d_ws;
  const size_t WSZ = (size_t)DIM * DIM * sizeof(bf16);
  const size_t TSZ = (size_t)BATCH * SEQ * DIM * sizeof(bf16);
  bf16* Wq_b = (bf16*)(ws);
  bf16* Wk_b = (bf16*)(ws + WSZ);
  bf16* Wv_b = (bf16*)(ws + 2 * WSZ);
  bf16* Wo_b = (bf16*)(ws + 3 * WSZ);
  bf16* Q_b  = (bf16*)(ws + 4 * WSZ);
  bf16* K_b  = (bf16*)(ws + 4 * WSZ + TSZ);
  bf16* Vt_b = (bf16*)(ws + 4 * WSZ + 2 * TSZ);
  bf16* C_b  = (bf16*)(ws + 4 * WSZ + 3 * TSZ);

  cvt_w_kernel<<<dim3(DIM * DIM / (256 * 4), 4), 256, 0, stream>>>(
      Wq, Wk, Wv, Wo, Wq_b, Wk_b, Wv_b, Wo_b);

  ProjArgs pa;
  pa.A[0] = query; pa.A[1] = key_in; pa.A[2] = value;
  pa.W[0] = Wq_b;  pa.W[1] = Wk_b;   pa.W[2] = Wv_b;
  pa.bias[0] = bq; pa.bias[1] = bk;  pa.bias[2] = bv;
  pa.out[0] = Q_b; pa.out[1] = K_b;  pa.out[2] = Vt_b;
  proj_gemm<<<dim3(DIM / 128, BATCH * SEQ / 128, 3), 256, 0, stream>>>(pa);

  attn_kernel<<<dim3(SEQ / 128, BATCH * NH), 256, 0, stream>>>(Q_b, K_b, Vt_b, C_b);

  out_gemm<<<dim3(DIM / 128, BATCH * SEQ / 128), 256, 0, stream>>>(
      C_b, Wo_b, bo, (float*)d_out);
}